// Round 6
// baseline (226.890 us; speedup 1.0000x reference)
//
#include <hip/hip_runtime.h>
#include <math.h>

#define DEV __device__ __forceinline__

constexpr int IN   = 1024;   // input features (K)
constexpr int OUT  = 1024;   // output features (N)
constexpr int NC   = 8;      // GMM components
constexpr int MAXM = 96;     // max missing entries tracked per row (Poisson(20.5): P(>96) ~ 1e-40)
constexpr int CPB  = 512;    // cols per epilogue block
constexpr int KST  = 36;     // u16 stride per col in sW (72B: 8B-aligned for b64, bank-spread)

typedef __bf16 bf16x8 __attribute__((ext_vector_type(8)));
typedef float  f32x4  __attribute__((ext_vector_type(4)));
typedef float  f32x2  __attribute__((ext_vector_type(2)));
typedef unsigned int u32;

union ABf { bf16x8 v; u32 d[4]; unsigned short s[8]; };

DEV unsigned short f2bf(float f) {   // RNE float->bf16, input guaranteed non-NaN
  union { float f; u32 u; } v; v.f = f;
  u32 u = v.u;
  return (unsigned short)((u + 0x7FFFu + ((u >> 16) & 1u)) >> 16);
}

DEV float bfbits2f(u32 bits) {       // f32 whose high16 = bf16 bits
  union { u32 u; float f; } v; v.u = bits;
  return v.f;
}

DEV void gload_lds16(const void* g, void* l) {
  __builtin_amdgcn_global_load_lds(
      (__attribute__((address_space(1))) void*)(unsigned long long)(uintptr_t)g,
      (__attribute__((address_space(3))) void*)l,
      16, 0, 0);
}

// ---------------------------------------------------------------------------
// K1: per-row NaN scan. Writes bf16 x_clean, deterministic (sorted) missing
// index list per row via Hillis-Steele prefix sum.
// ---------------------------------------------------------------------------
__global__ __launch_bounds__(256) void prep_kernel(
    const float* __restrict__ x, unsigned short* __restrict__ xb,
    unsigned short* __restrict__ midx, int* __restrict__ counts) {
  const int row = blockIdx.x, t = threadIdx.x;
  __shared__ int ps[256];

  float4 v = ((const float4*)x)[row * (IN / 4) + t];  // cols 4t..4t+3
  bool n0 = (v.x != v.x), n1 = (v.y != v.y), n2 = (v.z != v.z), n3 = (v.w != v.w);

  ushort4 o;
  o.x = f2bf(n0 ? 0.f : v.x);
  o.y = f2bf(n1 ? 0.f : v.y);
  o.z = f2bf(n2 ? 0.f : v.z);
  o.w = f2bf(n3 ? 0.f : v.w);
  ((ushort4*)xb)[row * (IN / 4) + t] = o;

  int lc = (int)n0 + (int)n1 + (int)n2 + (int)n3;
  ps[t] = lc;
  __syncthreads();
  for (int off = 1; off < 256; off <<= 1) {
    int add = (t >= off) ? ps[t - off] : 0;
    __syncthreads();
    ps[t] += add;
    __syncthreads();
  }
  int pos = ps[t] - lc;  // exclusive prefix
  int col = 4 * t;
  if (n0) { if (pos < MAXM) midx[row * MAXM + pos] = (unsigned short)(col + 0); pos++; }
  if (n1) { if (pos < MAXM) midx[row * MAXM + pos] = (unsigned short)(col + 1); pos++; }
  if (n2) { if (pos < MAXM) midx[row * MAXM + pos] = (unsigned short)(col + 2); pos++; }
  if (n3) { if (pos < MAXM) midx[row * MAXM + pos] = (unsigned short)(col + 3); pos++; }
  if (t == 255) counts[row] = min(ps[255], MAXM);
}

// ---------------------------------------------------------------------------
// K1b: W [IN][OUT] f32 -> Wt [OUT][IN] bf16 (B^T layout for the MFMA GEMM).
// Block (0,0) additionally computes softmax(gw) -> p_ws[8] (row-independent).
// ---------------------------------------------------------------------------
__global__ __launch_bounds__(256) void transpose_w(
    const float* __restrict__ W, unsigned short* __restrict__ Wt,
    const float* __restrict__ gw, float* __restrict__ p_ws) {
  __shared__ float tile[32][33];
  const int k0 = blockIdx.x * 32, n0 = blockIdx.y * 32;
  const int tx = threadIdx.x, ty = threadIdx.y;

  if (k0 == 0 && n0 == 0 && tx == 0 && ty == 0) {
    float wmax = -1e30f;
    for (int i = 0; i < NC; ++i) wmax = fmaxf(wmax, gw[i]);
    float e[NC], s = 0.f;
    for (int i = 0; i < NC; ++i) { e[i] = expf(gw[i] - wmax); s += e[i]; }
    for (int i = 0; i < NC; ++i) p_ws[i] = e[i] / s;
  }

  for (int r = ty; r < 32; r += 8) tile[r][tx] = W[(k0 + r) * OUT + (n0 + tx)];
  __syncthreads();
  for (int r = ty; r < 32; r += 8) Wt[(n0 + r) * IN + (k0 + tx)] = f2bf(tile[tx][r]);
}

// ---------------------------------------------------------------------------
// K2: base = xb @ Wt^T  (A: MxK bf16 row-major, Bt: NxK bf16 row-major),
// C f32 row-major written to d_out. 128x128 tile, BK=32, 4 waves (2x2),
// global_load_lds width-16 staging (m97 structure). Unchanged.
// ---------------------------------------------------------------------------
__global__ __launch_bounds__(256) void gemm_base(
    const unsigned short* __restrict__ A, const unsigned short* __restrict__ Bt,
    float* __restrict__ C, int M) {
  __shared__ __align__(16) unsigned short sA[128 * 32];  // [row][k] 8 KB
  __shared__ __align__(16) unsigned short sB[128 * 32];  // [col][k] 8 KB

  const int t = threadIdx.x;
  const int lane = t & 63, w = t >> 6;
  const int wm = w >> 1, wn = w & 1;          // 2x2 wave grid, 64x64 per wave
  const int l15 = lane & 15, kblk = lane >> 4;
  const int row0 = blockIdx.x * 128, col0 = blockIdx.y * 128;

  const int r_a  = t >> 2;          // staging row 0..63
  const int cb_a = (t & 3) * 8;     // staging k-offset {0,8,16,24}

  f32x4 acc[4][4] = {};

  const int aoff = (wm * 64 + l15) * 32 + kblk * 8;  // short index for frag reads
  const int boff = (wn * 64 + l15) * 32 + kblk * 8;

  for (int k0 = 0; k0 < IN; k0 += 32) {
    __syncthreads();  // previous iteration's frag reads complete
    gload_lds16(&A[(size_t)(row0 + r_a) * IN + k0 + cb_a],       &sA[t * 8]);
    gload_lds16(&A[(size_t)(row0 + r_a + 64) * IN + k0 + cb_a],  &sA[2048 + t * 8]);
    gload_lds16(&Bt[(size_t)(col0 + r_a) * IN + k0 + cb_a],      &sB[t * 8]);
    gload_lds16(&Bt[(size_t)(col0 + r_a + 64) * IN + k0 + cb_a], &sB[2048 + t * 8]);
    __syncthreads();  // compiler drains vmcnt(0) before barrier -> staging done

    bf16x8 af[4], bfr[4];
#pragma unroll
    for (int mi = 0; mi < 4; ++mi) af[mi]  = *(const bf16x8*)&sA[aoff + mi * 16 * 32];
#pragma unroll
    for (int ni = 0; ni < 4; ++ni) bfr[ni] = *(const bf16x8*)&sB[boff + ni * 16 * 32];
#pragma unroll
    for (int mi = 0; mi < 4; ++mi)
#pragma unroll
      for (int ni = 0; ni < 4; ++ni)
        acc[mi][ni] = __builtin_amdgcn_mfma_f32_16x16x32_bf16(af[mi], bfr[ni], acc[mi][ni], 0, 0, 0);
  }

  // C/D layout: col = lane&15, row = (lane>>4)*4 + reg   [m89-verified]
#pragma unroll
  for (int mi = 0; mi < 4; ++mi)
#pragma unroll
    for (int ni = 0; ni < 4; ++ni) {
      int grow = row0 + wm * 64 + mi * 16 + kblk * 4;
      int gcol = col0 + wn * 64 + ni * 16 + l15;
#pragma unroll
      for (int r = 0; r < 4; ++r)
        C[(size_t)(grow + r) * OUT + gcol] = acc[mi][ni][r];
    }
}

// ---------------------------------------------------------------------------
// K3 (MFMA version): fused GMM epilogue, in-place on d_out.
// Grid (M, 2): block = (row, 512-col half). 4 waves; wave owns 128 cols
// = 8 MFMA col-tiles of 16.
//
// Per K-chunk of 32 missing slots:
//   A-op (M=16 cols x K=32)  = gathered W rows, bf16, staged col-major in LDS
//   A2-op                    = A squared in-register (bf16)
//   B-op (K=32 x N=16)       = (mean_i | cov_i) bf16: mean in N-cols 0..7,
//                              cov in N-cols 8..15; two MFMAs, one acc.
// C layout: N(comp)=lane&15, M(col)=(lane>>4)*4+reg.
// Epilogue: shfl_xor(8) pairs mean/cov halves; lanes n<8 eval cols r0,r1,
// lanes n>=8 eval cols r2,r3 (each (col,comp) exactly once); 3-step shfl_xor
// reduce over comps; lane i==0 stores f32x2.
// ---------------------------------------------------------------------------
__global__ __launch_bounds__(256) void epilogue_mfma(
    float* __restrict__ io, const float* __restrict__ W,
    const float* __restrict__ bvec, const float* __restrict__ p_ws,
    const float* __restrict__ gmean, const float* __restrict__ gcov,
    const unsigned short* __restrict__ midx, const int* __restrict__ counts) {
  __shared__ unsigned short sW[CPB * KST];   // 36.9 KB, [col][kk] bf16
  __shared__ u32 smcP[MAXM * NC];            // 3 KB, (bf16 mean)|(bf16 cov << 16)

  const int row = blockIdx.x;
  const int cb  = blockIdx.y * CPB;
  const int t   = threadIdx.x;
  const int lane = t & 63, wv = t >> 6;
  const int nn = lane & 15, ii = lane & 7, g = lane >> 4;
  const bool isCov = nn >= 8;
  const int rrb = isCov ? 2 : 0;

  const int m = counts[row];

  // preload base+bias for this lane's 2 cols per tile (overlaps staging)
  f32x2 basev[8];
#pragma unroll
  for (int tl = 0; tl < 8; ++tl) {
    int c = cb + wv * 128 + tl * 16 + g * 4 + rrb;
    f32x2 bb = *(const f32x2*)(io + (size_t)row * OUT + c);
    f32x2 bi = *(const f32x2*)(bvec + c);
    basev[tl][0] = bb[0] + bi[0];
    basev[tl][1] = bb[1] + bi[1];
  }

  if (m == 0) {  // full row: relu (uniform branch; essentially never taken)
#pragma unroll
    for (int tl = 0; tl < 8; ++tl) {
      if (ii == 0) {
        int c = cb + wv * 128 + tl * 16 + g * 4 + rrb;
        f32x2 o; o[0] = fmaxf(basev[tl][0], 0.f); o[1] = fmaxf(basev[tl][1], 0.f);
        *(f32x2*)(io + (size_t)row * OUT + c) = o;
      }
    }
    return;
  }

  const int nch = (m + 31) >> 5;

  // stage packed (mean,cov) bf16 pairs, zero-padded to nch*32 slots
  for (int idx = t; idx < nch * 32 * NC; idx += 256) {
    int tt = idx >> 3, i = idx & 7;
    u32 v = 0;
    if (tt < m) {
      int k = midx[(size_t)row * MAXM + tt];
      float mn = gmean[i * IN + k];
      float cv = fabsf(gcov[i * IN + k]);
      v = (u32)f2bf(mn) | ((u32)f2bf(cv) << 16);
    }
    smcP[tt * NC + i] = v;
  }

  f32x4 acc[8] = {};

  for (int ch = 0; ch < nch; ++ch) {
    if (ch) __syncthreads();  // prior chunk's A-frag reads complete

    // ---- stage gathered W rows (bf16) col-major: sW[col][kk] ----
    {
      int kk = t & 31;
      int tkk = ch * 32 + kk;
      int k = midx[(size_t)row * MAXM + min(tkk, m - 1)];  // clamped: finite pad
      const float* wrow = W + (size_t)k * OUT + cb;
      int cg = (t >> 5) * 4;   // interleaved col groups for bank spread
#pragma unroll
      for (int i2 = 0; i2 < 16; ++i2) {
        int col = cg + i2 * 32;
        float4 w4 = *(const float4*)(wrow + col);
        sW[(col + 0) * KST + kk] = f2bf(w4.x);
        sW[(col + 1) * KST + kk] = f2bf(w4.y);
        sW[(col + 2) * KST + kk] = f2bf(w4.z);
        sW[(col + 3) * KST + kk] = f2bf(w4.w);
      }
    }
    __syncthreads();  // sW + smcP visible

    // ---- build B fragments for this chunk ----
    ABf vals;
#pragma unroll
    for (int j = 0; j < 8; ++j) {
      u32 u = smcP[(ch * 32 + g * 8 + j) * NC + ii];
      vals.s[j] = (unsigned short)(isCov ? (u >> 16) : (u & 0xFFFFu));
    }
    ABf zf; zf.d[0] = zf.d[1] = zf.d[2] = zf.d[3] = 0;
    bf16x8 bm = isCov ? zf.v : vals.v;   // mean in N-cols 0..7
    bf16x8 bc = isCov ? vals.v : zf.v;   // cov  in N-cols 8..15

    // ---- 8 col-tiles: A read, square, 2 MFMAs ----
#pragma unroll
    for (int tl = 0; tl < 8; ++tl) {
      int colL = wv * 128 + tl * 16 + nn;
      ABf aw;
      *(uint2*)&aw.d[0] = *(const uint2*)&sW[colL * KST + g * 8];
      *(uint2*)&aw.d[2] = *(const uint2*)&sW[colL * KST + g * 8 + 4];
      ABf a2;
#pragma unroll
      for (int d = 0; d < 4; ++d) {
        u32 u = aw.d[d];
        float lo = bfbits2f(u << 16);
        float hi = bfbits2f(u & 0xFFFF0000u);
        a2.d[d] = (u32)f2bf(lo * lo) | ((u32)f2bf(hi * hi) << 16);
      }
      acc[tl] = __builtin_amdgcn_mfma_f32_16x16x32_bf16(aw.v, bm, acc[tl], 0, 0, 0);
      acc[tl] = __builtin_amdgcn_mfma_f32_16x16x32_bf16(a2.v, bc, acc[tl], 0, 0, 0);
    }
  }

  // ---- nr() epilogue ----
  const float INV_SQRT_2PI = 0.39894228040143268f;
  const float LOGI_K = 1.702f;
  const float L2E = 1.442695040888963f;
  const float pi_w = p_ws[ii];

#pragma unroll
  for (int tl = 0; tl < 8; ++tl) {
    f32x4 ac = acc[tl];
    float s0 = __shfl_xor(ac[0], 8);
    float s1 = __shfl_xor(ac[1], 8);
    float s2 = __shfl_xor(ac[2], 8);
    float s3 = __shfl_xor(ac[3], 8);
    // lanes n<8: eval cols reg0,reg1 (a own, var partner)
    // lanes n>=8: eval cols reg2,reg3 (a partner, var own)
    float A0 = isCov ? s2 : ac[0];
    float A1 = isCov ? s3 : ac[1];
    float V0 = isCov ? ac[2] : s0;
    float V1 = isCov ? ac[3] : s1;

    float t0, t1;
    {
      float a   = basev[tl][0] + A0;
      float rs  = (V0 > 0.f) ? __builtin_amdgcn_rsqf(V0) : 1.0f;
      float z   = a * rs;
      float eu  = __builtin_amdgcn_exp2f(-0.5f * L2E * z * z);
      float el  = __builtin_amdgcn_exp2f(-LOGI_K * L2E * z);
      float Phi = __builtin_amdgcn_rcpf(1.0f + el);
      t0 = pi_w * fmaf(z, Phi, INV_SQRT_2PI * eu);
    }
    {
      float a   = basev[tl][1] + A1;
      float rs  = (V1 > 0.f) ? __builtin_amdgcn_rsqf(V1) : 1.0f;
      float z   = a * rs;
      float eu  = __builtin_amdgcn_exp2f(-0.5f * L2E * z * z);
      float el  = __builtin_amdgcn_exp2f(-LOGI_K * L2E * z);
      float Phi = __builtin_amdgcn_rcpf(1.0f + el);
      t1 = pi_w * fmaf(z, Phi, INV_SQRT_2PI * eu);
    }
    // reduce over 8 comps (lane bits 0..2)
#pragma unroll
    for (int d = 1; d <= 4; d <<= 1) {
      t0 += __shfl_xor(t0, d);
      t1 += __shfl_xor(t1, d);
    }
    if (ii == 0) {
      int c = cb + wv * 128 + tl * 16 + g * 4 + rrb;
      f32x2 o; o[0] = t0; o[1] = t1;
      *(f32x2*)(io + (size_t)row * OUT + c) = o;
    }
  }
}

// ---------------------------------------------------------------------------
extern "C" void kernel_launch(void* const* d_in, const int* in_sizes, int n_in,
                              void* d_out, int out_size, void* d_ws, size_t ws_size,
                              hipStream_t stream) {
  const float* x  = (const float*)d_in[0];
  const float* W  = (const float*)d_in[1];
  const float* b  = (const float*)d_in[2];
  const float* gw = (const float*)d_in[3];
  const float* gm = (const float*)d_in[4];
  const float* gc = (const float*)d_in[5];
  float* out = (float*)d_out;
  const int M = in_sizes[0] / IN;  // 8192

  // workspace layout
  char* ws = (char*)d_ws;
  unsigned short* xb   = (unsigned short*)ws;                              // M*IN*2   = 16 MB
  unsigned short* Wt   = (unsigned short*)(ws + (size_t)M * IN * 2);       // IN*OUT*2 =  2 MB
  unsigned short* midx = (unsigned short*)(ws + (size_t)M * IN * 2 + (size_t)IN * OUT * 2);  // M*MAXM*2
  int* counts = (int*)(ws + (size_t)M * IN * 2 + (size_t)IN * OUT * 2 + (size_t)M * MAXM * 2);
  float* p_ws = (float*)(ws + (size_t)M * IN * 2 + (size_t)IN * OUT * 2 + (size_t)M * MAXM * 2 + (size_t)M * 4);

  prep_kernel<<<M, 256, 0, stream>>>(x, xb, midx, counts);
  transpose_w<<<dim3(IN / 32, OUT / 32), dim3(32, 8), 0, stream>>>(W, Wt, gw, p_ws);
  gemm_base<<<dim3(M / 128, OUT / 128), 256, 0, stream>>>(xb, Wt, out, M);
  epilogue_mfma<<<dim3(M, 2), 256, 0, stream>>>(out, W, b, p_ws, gm, gc, midx, counts);
}

// Round 7
// 154.745 us; speedup vs baseline: 1.4662x; 1.4662x over previous
//
#include <hip/hip_runtime.h>
#include <math.h>

#define DEV __device__ __forceinline__

constexpr int IN   = 1024;   // input features (K)
constexpr int OUT  = 1024;   // output features (N)
constexpr int NC   = 8;      // GMM components
constexpr int MAXM = 96;     // max missing entries tracked per row (Poisson(20.5): P(>96) ~ 1e-40)

typedef __bf16 bf16x8 __attribute__((ext_vector_type(8)));
typedef float  f32x4  __attribute__((ext_vector_type(4)));
typedef float  f32x2  __attribute__((ext_vector_type(2)));

DEV unsigned short f2bf(float f) {   // RNE float->bf16, input guaranteed non-NaN
  union { float f; unsigned int u; } v; v.f = f;
  unsigned int u = v.u;
  return (unsigned short)((u + 0x7FFFu + ((u >> 16) & 1u)) >> 16);
}

DEV void gload_lds16(const void* g, void* l) {
  __builtin_amdgcn_global_load_lds(
      (__attribute__((address_space(1))) void*)(unsigned long long)(uintptr_t)g,
      (__attribute__((address_space(3))) void*)l,
      16, 0, 0);
}

// ---------------------------------------------------------------------------
// K1: per-row NaN scan. Writes bf16 x_clean, deterministic (sorted) missing
// index list per row via Hillis-Steele prefix sum.
// ---------------------------------------------------------------------------
__global__ __launch_bounds__(256) void prep_kernel(
    const float* __restrict__ x, unsigned short* __restrict__ xb,
    unsigned short* __restrict__ midx, int* __restrict__ counts) {
  const int row = blockIdx.x, t = threadIdx.x;
  __shared__ int ps[256];

  float4 v = ((const float4*)x)[row * (IN / 4) + t];  // cols 4t..4t+3
  bool n0 = (v.x != v.x), n1 = (v.y != v.y), n2 = (v.z != v.z), n3 = (v.w != v.w);

  ushort4 o;
  o.x = f2bf(n0 ? 0.f : v.x);
  o.y = f2bf(n1 ? 0.f : v.y);
  o.z = f2bf(n2 ? 0.f : v.z);
  o.w = f2bf(n3 ? 0.f : v.w);
  ((ushort4*)xb)[row * (IN / 4) + t] = o;

  int lc = (int)n0 + (int)n1 + (int)n2 + (int)n3;
  ps[t] = lc;
  __syncthreads();
  for (int off = 1; off < 256; off <<= 1) {
    int add = (t >= off) ? ps[t - off] : 0;
    __syncthreads();
    ps[t] += add;
    __syncthreads();
  }
  int pos = ps[t] - lc;  // exclusive prefix
  int col = 4 * t;
  if (n0) { if (pos < MAXM) midx[row * MAXM + pos] = (unsigned short)(col + 0); pos++; }
  if (n1) { if (pos < MAXM) midx[row * MAXM + pos] = (unsigned short)(col + 1); pos++; }
  if (n2) { if (pos < MAXM) midx[row * MAXM + pos] = (unsigned short)(col + 2); pos++; }
  if (n3) { if (pos < MAXM) midx[row * MAXM + pos] = (unsigned short)(col + 3); pos++; }
  if (t == 255) counts[row] = min(ps[255], MAXM);
}

// ---------------------------------------------------------------------------
// K1b: W [IN][OUT] f32 -> Wt [OUT][IN] bf16 (B^T layout for the MFMA GEMM).
// Block (0,0) additionally computes softmax(gw) -> p_ws[8] (row-independent).
// ---------------------------------------------------------------------------
__global__ __launch_bounds__(256) void transpose_w(
    const float* __restrict__ W, unsigned short* __restrict__ Wt,
    const float* __restrict__ gw, float* __restrict__ p_ws) {
  __shared__ float tile[32][33];
  const int k0 = blockIdx.x * 32, n0 = blockIdx.y * 32;
  const int tx = threadIdx.x, ty = threadIdx.y;

  if (k0 == 0 && n0 == 0 && tx == 0 && ty == 0) {
    float wmax = -1e30f;
    for (int i = 0; i < NC; ++i) wmax = fmaxf(wmax, gw[i]);
    float e[NC], s = 0.f;
    for (int i = 0; i < NC; ++i) { e[i] = expf(gw[i] - wmax); s += e[i]; }
    for (int i = 0; i < NC; ++i) p_ws[i] = e[i] / s;
  }

  for (int r = ty; r < 32; r += 8) tile[r][tx] = W[(k0 + r) * OUT + (n0 + tx)];
  __syncthreads();
  for (int r = ty; r < 32; r += 8) Wt[(n0 + r) * IN + (k0 + tx)] = f2bf(tile[tx][r]);
}

// ---------------------------------------------------------------------------
// K2: base = xb @ Wt^T  (A: MxK bf16 row-major, Bt: NxK bf16 row-major),
// C f32 row-major written to d_out. 128x128 tile, BK=32, 4 waves (2x2),
// global_load_lds width-16 staging (m97 structure). Unchanged since R1.
// ---------------------------------------------------------------------------
__global__ __launch_bounds__(256) void gemm_base(
    const unsigned short* __restrict__ A, const unsigned short* __restrict__ Bt,
    float* __restrict__ C, int M) {
  __shared__ __align__(16) unsigned short sA[128 * 32];  // [row][k] 8 KB
  __shared__ __align__(16) unsigned short sB[128 * 32];  // [col][k] 8 KB

  const int t = threadIdx.x;
  const int lane = t & 63, w = t >> 6;
  const int wm = w >> 1, wn = w & 1;          // 2x2 wave grid, 64x64 per wave
  const int l15 = lane & 15, kblk = lane >> 4;
  const int row0 = blockIdx.x * 128, col0 = blockIdx.y * 128;

  const int r_a  = t >> 2;          // staging row 0..63
  const int cb_a = (t & 3) * 8;     // staging k-offset {0,8,16,24}

  f32x4 acc[4][4] = {};

  const int aoff = (wm * 64 + l15) * 32 + kblk * 8;  // short index for frag reads
  const int boff = (wn * 64 + l15) * 32 + kblk * 8;

  for (int k0 = 0; k0 < IN; k0 += 32) {
    __syncthreads();  // previous iteration's frag reads complete
    gload_lds16(&A[(size_t)(row0 + r_a) * IN + k0 + cb_a],       &sA[t * 8]);
    gload_lds16(&A[(size_t)(row0 + r_a + 64) * IN + k0 + cb_a],  &sA[2048 + t * 8]);
    gload_lds16(&Bt[(size_t)(col0 + r_a) * IN + k0 + cb_a],      &sB[t * 8]);
    gload_lds16(&Bt[(size_t)(col0 + r_a + 64) * IN + k0 + cb_a], &sB[2048 + t * 8]);
    __syncthreads();  // compiler drains vmcnt(0) before barrier -> staging done

    bf16x8 af[4], bfr[4];
#pragma unroll
    for (int mi = 0; mi < 4; ++mi) af[mi]  = *(const bf16x8*)&sA[aoff + mi * 16 * 32];
#pragma unroll
    for (int ni = 0; ni < 4; ++ni) bfr[ni] = *(const bf16x8*)&sB[boff + ni * 16 * 32];
#pragma unroll
    for (int mi = 0; mi < 4; ++mi)
#pragma unroll
      for (int ni = 0; ni < 4; ++ni)
        acc[mi][ni] = __builtin_amdgcn_mfma_f32_16x16x32_bf16(af[mi], bfr[ni], acc[mi][ni], 0, 0, 0);
  }

  // C/D layout: col = lane&15, row = (lane>>4)*4 + reg   [m89-verified]
#pragma unroll
  for (int mi = 0; mi < 4; ++mi)
#pragma unroll
    for (int ni = 0; ni < 4; ++ni) {
      int grow = row0 + wm * 64 + mi * 16 + kblk * 4;
      int gcol = col0 + wn * 64 + ni * 16 + l15;
#pragma unroll
      for (int r = 0; r < 4; ++r)
        C[(size_t)(grow + r) * OUT + gcol] = acc[mi][ni][r];
    }
}

// ---------------------------------------------------------------------------
// K3: fused GMM epilogue, in-place on d_out (R4 structure). One block per row;
// thread t owns cols [4t..4t+3]. Accumulation via inline-asm v_fmac_f32 with
// "+v" constraints: forces all 64 accumulator floats into ARCH VGPRs (no
// AGPR parking / v_accvgpr_read-write shuffle, which inflated R2-R5 VALU ~2x).
// 1-deep W-row prefetch hides the ~200cyc L2-hit latency under the FMA body.
// nr(z) via logistic Phi (|err|<=~0.02 << 2.18 threshold).
// ---------------------------------------------------------------------------
__global__ __launch_bounds__(256, 4) void epilogue_kernel(
    float* __restrict__ io, const float* __restrict__ W,
    const float* __restrict__ bvec, const float* __restrict__ p_ws,
    const float* __restrict__ gmean, const float* __restrict__ gcov,
    const unsigned short* __restrict__ midx, const int* __restrict__ counts) {
  const int row = blockIdx.x, t = threadIdx.x;
  __shared__ f32x2 smc[MAXM][NC];        // (mean, |cov|) pairs, b64 broadcast
  __shared__ unsigned short skidx[MAXM];

  const int m = counts[row];

  f32x4 base = *(const f32x4*)(io + (size_t)row * OUT + 4 * t);
  base = base + *(const f32x4*)(bvec + 4 * t);

  if (m == 0) {  // full row: relu path (uniform branch; essentially never taken)
    f32x4 r;
#pragma unroll
    for (int c = 0; c < 4; ++c) r[c] = fmaxf(base[c], 0.0f);
    *(f32x4*)(io + (size_t)row * OUT + 4 * t) = r;
    return;
  }

  // row-independent mixture weights, precomputed in transpose_w
  f32x4 p0 = *(const f32x4*)(p_ws);
  f32x4 p1 = *(const f32x4*)(p_ws + 4);

  // stage gathered (mean,|cov|) pairs and k indices for this row
  for (int idx = t; idx < m * NC; idx += 256) {
    int tt = idx >> 3, i = idx & 7;
    int k = midx[row * MAXM + tt];
    f32x2 mc;
    mc[0] = gmean[i * IN + k];
    mc[1] = fabsf(gcov[i * IN + k]);
    smc[tt][i] = mc;
  }
  for (int idx = t; idx < m; idx += 256) skidx[idx] = midx[row * MAXM + idx];
  __syncthreads();

  float accA[NC][4] = {};
  float accV[NC][4] = {};

  int kcur = __builtin_amdgcn_readfirstlane((int)skidx[0]);
  f32x4 wv = *(const f32x4*)(W + ((size_t)kcur << 10) + 4 * t);

  for (int tt = 0; tt < m; ++tt) {
    // prefetch next W row (clamped on last iter; wave-uniform k -> SGPR base)
    int kn = __builtin_amdgcn_readfirstlane((int)skidx[min(tt + 1, m - 1)]);
    f32x4 wnx = *(const f32x4*)(W + ((size_t)kn << 10) + 4 * t);

    f32x4 w2 = wv * wv;
#pragma unroll
    for (int i = 0; i < NC; ++i) {
      f32x2 mc = smc[tt][i];            // one ds_read_b64 broadcast
      float mu = mc[0], cv = mc[1];
#pragma unroll
      for (int c = 0; c < 4; ++c) {
        asm("v_fmac_f32 %0, %1, %2" : "+v"(accA[i][c]) : "v"(mu), "v"(wv[c]));
        asm("v_fmac_f32 %0, %1, %2" : "+v"(accV[i][c]) : "v"(cv), "v"(w2[c]));
      }
    }
    wv = wnx;
  }

  const float INV_SQRT_2PI = 0.39894228040143268f;
  const float LOGI_K       = 1.702f;           // logistic CDF slope
  const float L2E          = 1.442695040888963f;

  f32x4 out = {};
#pragma unroll
  for (int i = 0; i < NC; ++i) {
    float pi = (i < 4) ? p0[i & 3] : p1[i & 3];
#pragma unroll
    for (int c = 0; c < 4; ++c) {
      float a   = base[c] + accA[i][c];
      float var = accV[i][c];
      float rs  = (var > 0.f) ? __builtin_amdgcn_rsqf(var) : 1.0f;
      float z   = a * rs;
      // phi(z) = exp(-z^2/2)/sqrt(2pi)   [exp2-based]
      float eu  = __builtin_amdgcn_exp2f(-0.5f * L2E * z * z);
      float phi = INV_SQRT_2PI * eu;
      // Phi(z) ~= 1/(1+exp(-1.702 z))
      float el  = __builtin_amdgcn_exp2f(-LOGI_K * L2E * z);
      float Phi = __builtin_amdgcn_rcpf(1.0f + el);
      float nrv = fmaf(z, Phi, phi);
      out[c] = fmaf(pi, nrv, out[c]);
    }
  }
  *(f32x4*)(io + (size_t)row * OUT + 4 * t) = out;
}

// ---------------------------------------------------------------------------
extern "C" void kernel_launch(void* const* d_in, const int* in_sizes, int n_in,
                              void* d_out, int out_size, void* d_ws, size_t ws_size,
                              hipStream_t stream) {
  const float* x  = (const float*)d_in[0];
  const float* W  = (const float*)d_in[1];
  const float* b  = (const float*)d_in[2];
  const float* gw = (const float*)d_in[3];
  const float* gm = (const float*)d_in[4];
  const float* gc = (const float*)d_in[5];
  float* out = (float*)d_out;
  const int M = in_sizes[0] / IN;  // 8192

  // workspace layout
  char* ws = (char*)d_ws;
  unsigned short* xb   = (unsigned short*)ws;                              // M*IN*2   = 16 MB
  unsigned short* Wt   = (unsigned short*)(ws + (size_t)M * IN * 2);       // IN*OUT*2 =  2 MB
  unsigned short* midx = (unsigned short*)(ws + (size_t)M * IN * 2 + (size_t)IN * OUT * 2);  // M*MAXM*2
  int* counts = (int*)(ws + (size_t)M * IN * 2 + (size_t)IN * OUT * 2 + (size_t)M * MAXM * 2);
  float* p_ws = (float*)(ws + (size_t)M * IN * 2 + (size_t)IN * OUT * 2 + (size_t)M * MAXM * 2 + (size_t)M * 4);

  prep_kernel<<<M, 256, 0, stream>>>(x, xb, midx, counts);
  transpose_w<<<dim3(IN / 32, OUT / 32), dim3(32, 8), 0, stream>>>(W, Wt, gw, p_ws);
  gemm_base<<<dim3(M / 128, OUT / 128), 256, 0, stream>>>(xb, Wt, out, M);
  epilogue_kernel<<<M, 256, 0, stream>>>(out, W, b, p_ws, gm, gc, midx, counts);
}